// Round 14
// baseline (219.965 us; speedup 1.0000x reference)
//
#include <hip/hip_runtime.h>
#include <math.h>

#define T_DIM 64
#define C_DIM 256
#define H_DIM 56
#define W_DIM 56
#define HW    (H_DIM * W_DIM)        // 3136
#define HW4   (HW / 4)               // 784
#define CHW   (C_DIM * HW)
#define THW   (T_DIM * HW)           // 200704
#define PL4   (THW / 4)              // 50176 float4 per plane
#define TS4   (C_DIM * HW4)          // float4 per t-plane
#define NGATE 1024
#define NCOPY 1568

typedef float nt_float4 __attribute__((ext_vector_type(4)));

__device__ __forceinline__ float rfl(float v) {
    return __int_as_float(__builtin_amdgcn_readfirstlane(__float_as_int(v)));
}

// ---------------------------------------------------------------------------
// K1: gate blocks [0,1024) + copy blocks [1024, 2592).
// Gate: p -> xcd = p&7, j = p>>3, gq = j&3, tileL = j>>2 (tl, side, hh).
//   The 4 gq blocks of one tile are p, p+8, p+16, p+24 -> same XCD (p%8 law),
//   so the last-block finish reads its 3 sibling partials from that XCD's L2.
//   Gate core: 4 waves x 4ch, rfl->SGPR weights, shfl halo, LDS reduce ->
//   partial plane pbuf[side*4+gq]. threadfence + atomic counter; last block
//   of the tile sums 4 partials + bias + tanh -> gbuf (no reduce kernel).
// Copy: NT passthrough of the c>=128 half (16 t's per thread).
// ---------------------------------------------------------------------------
__global__ __launch_bounds__(256) void gate_copy_kernel(
    const float* __restrict__ x,
    const float* __restrict__ w_l,
    const float* __restrict__ b_l,
    const float* __restrict__ w_r,
    const float* __restrict__ b_r,
    float* __restrict__ pbuf,
    float* __restrict__ gbuf,
    float* __restrict__ out,
    unsigned int* __restrict__ cnt)
{
    const int p   = blockIdx.x;
    const int tid = threadIdx.x;

    if (p >= NGATE) {
        // ---------------- copy path: c >= 128 ----------------
        const int qq     = p - NGATE;          // [0, 1568)
        const int tchunk = qq / 392;
        const int bx2    = qq - tchunk * 392;
        const int col    = 128 * HW4 + bx2 * 256 + tid;
        const int t0     = tchunk * 16;

        const nt_float4* xn4 = (const nt_float4*)x;
        nt_float4*       on4 = (nt_float4*)out;

        #pragma unroll 4
        for (int i = 0; i < 16; ++i) {
            const size_t idx = (size_t)(t0 + i) * TS4 + col;
            nt_float4 v = __builtin_nontemporal_load(&xn4[idx]);
            __builtin_nontemporal_store(v, &on4[idx]);
        }
        return;
    }

    // ---------------- gate path ----------------
    __shared__ float4 red[4][7][64];   // 28672 B
    __shared__ int    lastflag;

    const int xcd   = p & 7;
    const int j     = p >> 3;          // [0,128)
    const int gq    = j & 3;
    const int tileL = j >> 2;          // [0,32)
    const int tl    = tileL & 7;
    const int side  = (tileL >> 3) & 1;
    const int hh    = tileL >> 4;
    const int t     = xcd * 8 + tl;

    const int waveid = __builtin_amdgcn_readfirstlane(tid >> 6);
    const int lane = tid & 63;
    const int wg   = lane & 15;
    const int rg   = lane >> 4;
    const bool act = (wg < 14);
    const int w0   = act ? wg * 4 : 52;
    const int r0   = hh * 28 + rg * 7;
    const bool have_l = (wg > 0);
    const bool have_r = (wg < 13);

    const int cw = gq * 16 + waveid * 4;           // channel base in half
    const float* wtab = (side ? w_r : w_l) + cw * 27;
    const int c0 = side * 64 + cw;

    const int tm = (t + 63) & 63, tp = (t + 1) & 63;
    const float* tbase[3] = { x + (size_t)tm * CHW,
                              x + (size_t)t  * CHW,
                              x + (size_t)tp * CHW };

    float acc[7][4];
    #pragma unroll
    for (int jj = 0; jj < 7; ++jj)
        #pragma unroll
        for (int k = 0; k < 4; ++k) acc[jj][k] = 0.f;

    #pragma unroll 1
    for (int ci = 0; ci < 4; ++ci) {
        float wgt[27];
        #pragma unroll
        for (int k = 0; k < 27; ++k) wgt[k] = rfl(wtab[ci * 27 + k]);  // SGPRs

        #pragma unroll
        for (int dt = 0; dt < 3; ++dt) {
            const float* plane = tbase[dt] + (size_t)(c0 + ci) * HW;

            #pragma unroll
            for (int s9 = 0; s9 < 9; ++s9) {
                const int sr = r0 - 1 + s9;
                bool rv = true;
                int  srow = sr;
                if (s9 == 0)      { rv = (sr >= 0);     srow = rv ? sr : 0; }
                else if (s9 == 8) { rv = (sr < H_DIM);  srow = rv ? sr : (H_DIM - 1); }

                const float* row = plane + srow * W_DIM;
                float4 m  = *(const float4*)(row + w0);
                float  fl = __shfl_up(m.w, 1);    // row[w0-1]
                float  fr = __shfl_down(m.x, 1);  // row[w0+4]

                float f0 = have_l ? fl : 0.f;
                float f1 = m.x, f2 = m.y, f3 = m.z, f4v = m.w;
                float f5 = have_r ? fr : 0.f;
                if ((s9 == 0 || s9 == 8) && !rv) {
                    f0 = 0.f; f1 = 0.f; f2 = 0.f; f3 = 0.f; f4v = 0.f; f5 = 0.f;
                }
                float f[6] = { f0, f1, f2, f3, f4v, f5 };

                const int jlo = (s9 >= 2) ? s9 - 2 : 0;
                const int jhi = (s9 <= 6) ? s9 : 6;
                #pragma unroll
                for (int jj = jlo; jj <= jhi; ++jj) {
                    const int dh = s9 - jj;
                    const float w0t = wgt[dt * 9 + dh * 3 + 0];
                    const float w1t = wgt[dt * 9 + dh * 3 + 1];
                    const float w2t = wgt[dt * 9 + dh * 3 + 2];
                    #pragma unroll
                    for (int k = 0; k < 4; ++k)
                        acc[jj][k] += w0t * f[k] + w1t * f[k + 1] + w2t * f[k + 2];
                }
            }
        }
    }

    // ---- 4-wave LDS reduce -> partial plane ----
    #pragma unroll
    for (int jj = 0; jj < 7; ++jj) {
        float4 v; v.x = acc[jj][0]; v.y = acc[jj][1];
                  v.z = acc[jj][2]; v.w = acc[jj][3];
        red[waveid][jj][lane] = v;
    }
    __syncthreads();

    const int sg = side * 4 + gq;
    if (waveid == 0) {
        if (act) {
            float* pp = pbuf + (size_t)sg * THW
                             + (size_t)t * HW + r0 * W_DIM + w0;
            #pragma unroll
            for (int jj = 0; jj < 7; ++jj) {
                float4 a = red[0][jj][lane], b2 = red[1][jj][lane];
                float4 c = red[2][jj][lane], d  = red[3][jj][lane];
                float4 v;
                v.x = (a.x + b2.x) + (c.x + d.x);
                v.y = (a.y + b2.y) + (c.y + d.y);
                v.z = (a.z + b2.z) + (c.z + d.z);
                v.w = (a.w + b2.w) + (c.w + d.w);
                *(float4*)(pp + jj * W_DIM) = v;
            }
        }
        __threadfence();                       // wave-wide: covers all lanes' stores
        if (tid == 0) {
            unsigned old = atomicAdd(&cnt[xcd * 32 + tileL], 1u);
            lastflag = (old == 3u);
        }
    }
    __syncthreads();

    if (lastflag) {
        // last block of this tile: sum 4 partials (L2-hot) + bias + tanh
        __threadfence();
        const float bias = side ? b_r[0] : b_l[0];
        const float4* p4 = (const float4*)pbuf;
        float4* g4 = (float4*)gbuf;
        const int base4 = t * HW4 + hh * 392;  // contiguous 392-float4 region

        for (int i = tid; i < 392; i += 256) {
            float4 a = p4[(size_t)(side * 4 + 0) * PL4 + base4 + i];
            float4 b = p4[(size_t)(side * 4 + 1) * PL4 + base4 + i];
            float4 c = p4[(size_t)(side * 4 + 2) * PL4 + base4 + i];
            float4 d = p4[(size_t)(side * 4 + 3) * PL4 + base4 + i];
            float4 v;
            v.x = tanhf((a.x + b.x) + (c.x + d.x) + bias);
            v.y = tanhf((a.y + b.y) + (c.y + d.y) + bias);
            v.z = tanhf((a.z + b.z) + (c.z + d.z) + bias);
            v.w = tanhf((a.w + b.w) + (c.w + d.w) + bias);
            g4[(size_t)side * PL4 + base4 + i] = v;
        }
    }
}

// ---------------------------------------------------------------------------
// K2: combine (c < 128): thread owns (c,h,w4), iterates 16 t's carrying
// x/g in registers; NT stores. x reads are L3-warm from K1.
// ---------------------------------------------------------------------------
__global__ __launch_bounds__(256) void combine_kernel(
    const float* __restrict__ x,
    const float* __restrict__ g,
    float* __restrict__ out)
{
    const int tid = blockIdx.x * 256 + threadIdx.x;   // c in [0,128)
    const int t0  = blockIdx.y * 16;
    const int c   = tid / HW4;
    const int gb  = tid - c * HW4;

    const float4* x4 = (const float4*)x;
    nt_float4*    on4 = (nt_float4*)out;
    const size_t  base = tid;

    if (c < 64) {
        const float4* gl4 = (const float4*)g;
        float4 xv = x4[(size_t)t0 * TS4 + base];
        float4 g0 = gl4[t0 * HW4 + gb];
        #pragma unroll 4
        for (int i = 0; i < 16; ++i) {
            const int t  = t0 + i;
            const int tp = (t + 1) & 63;
            float4 xn = x4[(size_t)tp * TS4 + base];
            float4 g1 = gl4[tp * HW4 + gb];
            nt_float4 r;
            r.x = xv.x - g0.x * xv.x + g1.x * xn.x;
            r.y = xv.y - g0.y * xv.y + g1.y * xn.y;
            r.z = xv.z - g0.z * xv.z + g1.z * xn.z;
            r.w = xv.w - g0.w * xv.w + g1.w * xn.w;
            __builtin_nontemporal_store(r, &on4[(size_t)t * TS4 + base]);
            xv = xn; g0 = g1;
        }
    } else {
        const float4* gr4 = (const float4*)(g + THW);
        const int tmi = (t0 + 63) & 63;
        float4 xm = x4[(size_t)tmi * TS4 + base];
        float4 gm = gr4[tmi * HW4 + gb];
        #pragma unroll 4
        for (int i = 0; i < 16; ++i) {
            const int t = t0 + i;
            float4 xv = x4[(size_t)t * TS4 + base];
            float4 g0 = gr4[t * HW4 + gb];
            nt_float4 r;
            r.x = xv.x - g0.x * xv.x + gm.x * xm.x;
            r.y = xv.y - g0.y * xv.y + gm.y * xm.y;
            r.z = xv.z - g0.z * xv.z + gm.z * xm.z;
            r.w = xv.w - g0.w * xv.w + gm.w * xm.w;
            __builtin_nontemporal_store(r, &on4[(size_t)t * TS4 + base]);
            xm = xv; gm = g0;
        }
    }
}

extern "C" void kernel_launch(void* const* d_in, const int* in_sizes, int n_in,
                              void* d_out, int out_size, void* d_ws, size_t ws_size,
                              hipStream_t stream) {
    const float* x   = (const float*)d_in[0];
    const float* w_l = (const float*)d_in[1];
    const float* b_l = (const float*)d_in[2];
    const float* w_r = (const float*)d_in[3];
    const float* b_r = (const float*)d_in[4];
    float* out  = (float*)d_out;
    float* ws   = (float*)d_ws;

    float* pbuf = ws;                            // 8 partial planes (6.4 MB)
    float* gbuf = ws + (size_t)8 * THW;          // 2 gate planes  (1.6 MB)
    unsigned int* cnt = (unsigned int*)(ws + (size_t)10 * THW);  // 256 counters

    hipMemsetAsync(cnt, 0, 256 * sizeof(unsigned int), stream);

    gate_copy_kernel<<<NGATE + NCOPY, 256, 0, stream>>>(
        x, w_l, b_l, w_r, b_r, pbuf, gbuf, out, cnt);

    combine_kernel<<<dim3(392, 4), 256, 0, stream>>>(x, gbuf, out);
}

// Round 15
// 113.583 us; speedup vs baseline: 1.9366x; 1.9366x over previous
//
#include <hip/hip_runtime.h>
#include <math.h>

#define T_DIM 64
#define C_DIM 256
#define H_DIM 56
#define W_DIM 56
#define HW    (H_DIM * W_DIM)        // 3136
#define HW4   (HW / 4)               // 784
#define CHW   (C_DIM * HW)
#define THW   (T_DIM * HW)           // 200704
#define PL4   (THW / 4)              // float4 per gate plane
#define TS4   (C_DIM * HW4)          // float4 per t-plane
#define NGATE 256
#define NCOPY 784                    // 100352 cols / 512 thr * 4 t-chunks

typedef float nt_float4 __attribute__((ext_vector_type(4)));

__device__ __forceinline__ float rfl(float v) {
    return __int_as_float(__builtin_amdgcn_readfirstlane(__float_as_int(v)));
}

// ---------------------------------------------------------------------------
// K1 (512 thr): gate blocks [0,256) + copy blocks [256,1040).
// Gate: block = (side,t,hh); 8 waves x 8 channels; two-stage LDS reduce
//   (8->4->1) -> bias+tanh -> gbuf directly. No pbuf, no fences.
//   XCD swizzle: xcd = p&7 owns t in [xcd*8, xcd*8+8) -> t-halo L2 reuse.
//   Weights -> SGPRs via readfirstlane; shfl halo (1 float4 load per row).
// Copy: NT passthrough of the c>=128 half, 16 t's per thread.
// __launch_bounds__(512,2): 2 waves/EU floor -> VGPR budget 256 (avoids the
// empirically-confirmed 64-VGPR spill trap at higher wave/EU targets).
// ---------------------------------------------------------------------------
__global__ __launch_bounds__(512, 2) void gate_copy_kernel(
    const float* __restrict__ x,
    const float* __restrict__ w_l,
    const float* __restrict__ b_l,
    const float* __restrict__ w_r,
    const float* __restrict__ b_r,
    float* __restrict__ gbuf,
    float* __restrict__ out)
{
    const int p   = blockIdx.x;
    const int tid = threadIdx.x;

    if (p >= NGATE) {
        // ---------------- copy path: c >= 128 ----------------
        const int qq     = p - NGATE;          // [0, 784)
        const int tchunk = qq / 196;
        const int bx2    = qq - tchunk * 196;
        const int col    = 128 * HW4 + bx2 * 512 + tid;
        const int t0     = tchunk * 16;

        const nt_float4* xn4 = (const nt_float4*)x;
        nt_float4*       on4 = (nt_float4*)out;

        #pragma unroll 4
        for (int i = 0; i < 16; ++i) {
            const size_t idx = (size_t)(t0 + i) * TS4 + col;
            nt_float4 v = __builtin_nontemporal_load(&xn4[idx]);
            __builtin_nontemporal_store(v, &on4[idx]);
        }
        return;
    }

    // ---------------- gate path ----------------
    __shared__ float4 red[4][7][64];   // 28672 B

    const int xcd  = p & 7;
    const int rr   = p >> 3;           // [0,32)
    const int tl   = rr & 7;
    const int side = (rr >> 3) & 1;
    const int hh   = rr >> 4;
    const int t    = xcd * 8 + tl;

    const int waveid = __builtin_amdgcn_readfirstlane(tid >> 6);   // 0..7
    const int lane = tid & 63;
    const int wg   = lane & 15;
    const int rg   = lane >> 4;
    const bool act = (wg < 14);
    const int w0   = act ? wg * 4 : 52;
    const int r0   = hh * 28 + rg * 7;
    const bool have_l = (wg > 0);
    const bool have_r = (wg < 13);

    const int cw = waveid * 8;                     // channel base in half
    const float* wtab = (side ? w_r : w_l) + cw * 27;
    const int c0 = side * 64 + cw;

    const int tm = (t + 63) & 63, tp = (t + 1) & 63;
    const float* tbase[3] = { x + (size_t)tm * CHW,
                              x + (size_t)t  * CHW,
                              x + (size_t)tp * CHW };

    float acc[7][4];
    #pragma unroll
    for (int jj = 0; jj < 7; ++jj)
        #pragma unroll
        for (int k = 0; k < 4; ++k) acc[jj][k] = 0.f;

    #pragma unroll 1
    for (int ci = 0; ci < 8; ++ci) {
        float wgt[27];
        #pragma unroll
        for (int k = 0; k < 27; ++k) wgt[k] = rfl(wtab[ci * 27 + k]);  // SGPRs

        #pragma unroll
        for (int dt = 0; dt < 3; ++dt) {
            const float* plane = tbase[dt] + (size_t)(c0 + ci) * HW;

            #pragma unroll
            for (int s9 = 0; s9 < 9; ++s9) {
                const int sr = r0 - 1 + s9;
                bool rv = true;
                int  srow = sr;
                if (s9 == 0)      { rv = (sr >= 0);     srow = rv ? sr : 0; }
                else if (s9 == 8) { rv = (sr < H_DIM);  srow = rv ? sr : (H_DIM - 1); }

                const float* row = plane + srow * W_DIM;
                float4 m  = *(const float4*)(row + w0);
                float  fl = __shfl_up(m.w, 1);    // row[w0-1]
                float  fr = __shfl_down(m.x, 1);  // row[w0+4]

                float f0 = have_l ? fl : 0.f;
                float f1 = m.x, f2 = m.y, f3 = m.z, f4v = m.w;
                float f5 = have_r ? fr : 0.f;
                if ((s9 == 0 || s9 == 8) && !rv) {
                    f0 = 0.f; f1 = 0.f; f2 = 0.f; f3 = 0.f; f4v = 0.f; f5 = 0.f;
                }
                float f[6] = { f0, f1, f2, f3, f4v, f5 };

                const int jlo = (s9 >= 2) ? s9 - 2 : 0;
                const int jhi = (s9 <= 6) ? s9 : 6;
                #pragma unroll
                for (int jj = jlo; jj <= jhi; ++jj) {
                    const int dh = s9 - jj;
                    const float w0t = wgt[dt * 9 + dh * 3 + 0];
                    const float w1t = wgt[dt * 9 + dh * 3 + 1];
                    const float w2t = wgt[dt * 9 + dh * 3 + 2];
                    #pragma unroll
                    for (int k = 0; k < 4; ++k)
                        acc[jj][k] += w0t * f[k] + w1t * f[k + 1] + w2t * f[k + 2];
                }
            }
        }
    }

    // ---- two-stage LDS reduce: 8 -> 4 -> 1 ----
    if (waveid >= 4) {
        #pragma unroll
        for (int jj = 0; jj < 7; ++jj) {
            float4 v; v.x = acc[jj][0]; v.y = acc[jj][1];
                      v.z = acc[jj][2]; v.w = acc[jj][3];
            red[waveid - 4][jj][lane] = v;
        }
    }
    __syncthreads();
    if (waveid < 4) {
        #pragma unroll
        for (int jj = 0; jj < 7; ++jj) {
            float4 v = red[waveid][jj][lane];
            acc[jj][0] += v.x; acc[jj][1] += v.y;
            acc[jj][2] += v.z; acc[jj][3] += v.w;
        }
    }
    __syncthreads();
    if (waveid >= 1 && waveid < 4) {
        #pragma unroll
        for (int jj = 0; jj < 7; ++jj) {
            float4 v; v.x = acc[jj][0]; v.y = acc[jj][1];
                      v.z = acc[jj][2]; v.w = acc[jj][3];
            red[waveid][jj][lane] = v;
        }
    }
    __syncthreads();

    if (waveid == 0 && act) {
        const float bias = side ? b_r[0] : b_l[0];
        float* pp = gbuf + (size_t)side * THW
                         + (size_t)t * HW + r0 * W_DIM + w0;
        #pragma unroll
        for (int jj = 0; jj < 7; ++jj) {
            float4 a = red[1][jj][lane];
            float4 b = red[2][jj][lane];
            float4 c = red[3][jj][lane];
            float4 v;
            v.x = tanhf((acc[jj][0] + a.x) + (b.x + c.x) + bias);
            v.y = tanhf((acc[jj][1] + a.y) + (b.y + c.y) + bias);
            v.z = tanhf((acc[jj][2] + a.z) + (b.z + c.z) + bias);
            v.w = tanhf((acc[jj][3] + a.w) + (b.w + c.w) + bias);
            *(float4*)(pp + jj * W_DIM) = v;
        }
    }
}

// ---------------------------------------------------------------------------
// K2: combine (c < 128): thread owns (c,h,w4), iterates 16 t's carrying
// x/g in registers; NT stores. x reads are L3-warm from K1.
// ---------------------------------------------------------------------------
__global__ __launch_bounds__(256) void combine_kernel(
    const float* __restrict__ x,
    const float* __restrict__ g,
    float* __restrict__ out)
{
    const int tid = blockIdx.x * 256 + threadIdx.x;   // c in [0,128)
    const int t0  = blockIdx.y * 16;
    const int c   = tid / HW4;
    const int gb  = tid - c * HW4;

    const float4* x4 = (const float4*)x;
    nt_float4*    on4 = (nt_float4*)out;
    const size_t  base = tid;

    if (c < 64) {
        const float4* gl4 = (const float4*)g;
        float4 xv = x4[(size_t)t0 * TS4 + base];
        float4 g0 = gl4[t0 * HW4 + gb];
        #pragma unroll 4
        for (int i = 0; i < 16; ++i) {
            const int t  = t0 + i;
            const int tp = (t + 1) & 63;
            float4 xn = x4[(size_t)tp * TS4 + base];
            float4 g1 = gl4[tp * HW4 + gb];
            nt_float4 r;
            r.x = xv.x - g0.x * xv.x + g1.x * xn.x;
            r.y = xv.y - g0.y * xv.y + g1.y * xn.y;
            r.z = xv.z - g0.z * xv.z + g1.z * xn.z;
            r.w = xv.w - g0.w * xv.w + g1.w * xn.w;
            __builtin_nontemporal_store(r, &on4[(size_t)t * TS4 + base]);
            xv = xn; g0 = g1;
        }
    } else {
        const float4* gr4 = (const float4*)(g + THW);
        const int tmi = (t0 + 63) & 63;
        float4 xm = x4[(size_t)tmi * TS4 + base];
        float4 gm = gr4[tmi * HW4 + gb];
        #pragma unroll 4
        for (int i = 0; i < 16; ++i) {
            const int t = t0 + i;
            float4 xv = x4[(size_t)t * TS4 + base];
            float4 g0 = gr4[t * HW4 + gb];
            nt_float4 r;
            r.x = xv.x - g0.x * xv.x + gm.x * xm.x;
            r.y = xv.y - g0.y * xv.y + gm.y * xm.y;
            r.z = xv.z - g0.z * xv.z + gm.z * xm.z;
            r.w = xv.w - g0.w * xv.w + gm.w * xm.w;
            __builtin_nontemporal_store(r, &on4[(size_t)t * TS4 + base]);
            xm = xv; gm = g0;
        }
    }
}

extern "C" void kernel_launch(void* const* d_in, const int* in_sizes, int n_in,
                              void* d_out, int out_size, void* d_ws, size_t ws_size,
                              hipStream_t stream) {
    const float* x   = (const float*)d_in[0];
    const float* w_l = (const float*)d_in[1];
    const float* b_l = (const float*)d_in[2];
    const float* w_r = (const float*)d_in[3];
    const float* b_r = (const float*)d_in[4];
    float* out  = (float*)d_out;
    float* gbuf = (float*)d_ws;                // 2 gate planes = 1.6 MB

    gate_copy_kernel<<<NGATE + NCOPY, 512, 0, stream>>>(
        x, w_l, b_l, w_r, b_r, gbuf, out);

    combine_kernel<<<dim3(392, 4), 256, 0, stream>>>(x, gbuf, out);
}

// Round 16
// 107.108 us; speedup vs baseline: 2.0537x; 1.0604x over previous
//
#include <hip/hip_runtime.h>
#include <math.h>

#define T_DIM 64
#define C_DIM 256
#define H_DIM 56
#define W_DIM 56
#define HW    (H_DIM * W_DIM)        // 3136
#define HW4   (HW / 4)               // 784
#define CHW   (C_DIM * HW)
#define THW   (T_DIM * HW)           // 200704
#define PL4   (THW / 4)              // float4 per plane
#define TS4   (C_DIM * HW4)          // float4 per t-plane
#define NCOL  (128 * HW4)            // 100352 f4 per t in c>=128 half
#define NCOPY4 (T_DIM * NCOL)        // 6,422,528 copy float4s

typedef float nt_float4 __attribute__((ext_vector_type(4)));

__device__ __forceinline__ float rfl(float v) {
    return __int_as_float(__builtin_amdgcn_readfirstlane(__float_as_int(v)));
}

__device__ __forceinline__ void copy_f4(const nt_float4* xn4, nt_float4* on4,
                                        int i /* flat f4 idx in c>=128 region */) {
    const int tt = i / NCOL;
    const int rc = i - tt * NCOL;
    const size_t idx = (size_t)tt * TS4 + NCOL + rc;
    nt_float4 v = __builtin_nontemporal_load(&xn4[idx]);
    __builtin_nontemporal_store(v, &on4[idx]);
}

// ---------------------------------------------------------------------------
// K1: gate blocks [0, 2*S*32) with INTERLEAVED copy slice + trailing pure-copy
// blocks. Gate geometry = R10 exact (xcd-swizzled sg, 4 waves = (hh, 2 t's),
// CPG=64/S channel chain, rfl->SGPR weights, shfl halo, per-wave pbuf write).
// Each gate block also owns 4096 f4 of the c>=128 NT copy, issued KP=16/CPG
// pairs per channel iteration -> independent VMEM fills the gate's
// dependent-load stalls and the copy stream lasts exactly as long as the gate.
// ---------------------------------------------------------------------------
template<int S>
__global__ __launch_bounds__(256) void gate_copy_kernel(
    const float* __restrict__ x,
    const float* __restrict__ w_l,
    const float* __restrict__ w_r,
    float* __restrict__ pbuf,
    float* __restrict__ out)
{
    constexpr int CPG   = 64 / S;
    constexpr int KP    = 16 / CPG;        // copy pairs per ci iteration
    constexpr int NGATE = 2 * S * 32;

    const int p   = blockIdx.x;
    const int tid = threadIdx.x;
    const nt_float4* xn4 = (const nt_float4*)x;
    nt_float4*       on4 = (nt_float4*)out;

    if (p >= NGATE) {
        // trailing pure-copy blocks
        const int base = NGATE * 4096 + (p - NGATE) * 4096;
        #pragma unroll 4
        for (int k = 0; k < 16; ++k)
            copy_f4(xn4, on4, base + k * 256 + tid);
        return;
    }

    // ---------------- gate path (R10 geometry) ----------------
    const int xcd = p & 7;
    const int s   = p >> 3;
    const int sg  = xcd * (2 * S / 8) + (s >> 5);   // block-uniform
    const int tq  = s & 31;
    const int side = sg / S;
    const int g    = sg & (S - 1);

    const int cbase = p * 4096 + tid;               // this block's copy slice

    const int waveid = __builtin_amdgcn_readfirstlane(tid >> 6);
    const int hh = waveid & 1;
    const int t  = tq * 2 + (waveid >> 1);

    const int lane = tid & 63;
    const int wg   = lane & 15;
    const int rg   = lane >> 4;
    const bool act = (wg < 14);
    const int w0   = act ? wg * 4 : 52;
    const int r0   = hh * 28 + rg * 7;
    const bool have_l = (wg > 0);
    const bool have_r = (wg < 13);

    const float* wtab = (side ? w_r : w_l) + g * CPG * 27;   // uniform
    const int c0 = side * 64 + g * CPG;

    const int tm = (t + 63) & 63, tp = (t + 1) & 63;
    const float* tbase[3] = { x + (size_t)tm * CHW,
                              x + (size_t)t  * CHW,
                              x + (size_t)tp * CHW };

    float acc[7][4];
    #pragma unroll
    for (int j = 0; j < 7; ++j)
        #pragma unroll
        for (int k = 0; k < 4; ++k) acc[j][k] = 0.f;

    #pragma unroll 1
    for (int ci = 0; ci < CPG; ++ci) {
        // interleaved copy slice: independent VMEM to fill gate stalls
        #pragma unroll
        for (int k = 0; k < KP; ++k)
            copy_f4(xn4, on4, cbase + (ci * KP + k) * 256);

        float wgt[27];
        #pragma unroll
        for (int k = 0; k < 27; ++k) wgt[k] = rfl(wtab[ci * 27 + k]);  // SGPRs

        #pragma unroll
        for (int dt = 0; dt < 3; ++dt) {
            const float* plane = tbase[dt] + (size_t)(c0 + ci) * HW;

            #pragma unroll
            for (int s9 = 0; s9 < 9; ++s9) {
                const int sr = r0 - 1 + s9;
                bool rv = true;
                int  srow = sr;
                if (s9 == 0)      { rv = (sr >= 0);     srow = rv ? sr : 0; }
                else if (s9 == 8) { rv = (sr < H_DIM);  srow = rv ? sr : (H_DIM - 1); }

                const float* row = plane + srow * W_DIM;
                float4 m  = *(const float4*)(row + w0);
                float  fl = __shfl_up(m.w, 1);    // row[w0-1]
                float  fr = __shfl_down(m.x, 1);  // row[w0+4]

                float f0 = have_l ? fl : 0.f;
                float f1 = m.x, f2 = m.y, f3 = m.z, f4v = m.w;
                float f5 = have_r ? fr : 0.f;
                if ((s9 == 0 || s9 == 8) && !rv) {
                    f0 = 0.f; f1 = 0.f; f2 = 0.f; f3 = 0.f; f4v = 0.f; f5 = 0.f;
                }
                float f[6] = { f0, f1, f2, f3, f4v, f5 };

                const int jlo = (s9 >= 2) ? s9 - 2 : 0;
                const int jhi = (s9 <= 6) ? s9 : 6;
                #pragma unroll
                for (int j = jlo; j <= jhi; ++j) {
                    const int dh = s9 - j;
                    const float w0t = wgt[dt * 9 + dh * 3 + 0];
                    const float w1t = wgt[dt * 9 + dh * 3 + 1];
                    const float w2t = wgt[dt * 9 + dh * 3 + 2];
                    #pragma unroll
                    for (int k = 0; k < 4; ++k)
                        acc[j][k] += w0t * f[k] + w1t * f[k + 1] + w2t * f[k + 2];
                }
            }
        }
    }

    if (act) {
        float* pp = pbuf + (size_t)sg * THW
                         + (size_t)t * HW + r0 * W_DIM + w0;
        #pragma unroll
        for (int j = 0; j < 7; ++j) {
            float4 v; v.x = acc[j][0]; v.y = acc[j][1]; v.z = acc[j][2]; v.w = acc[j][3];
            *(float4*)(pp + j * W_DIM) = v;
        }
    }
}

// ---------------------------------------------------------------------------
// K2: reduce S partials per side + bias + tanh -> gbuf (gl at 0, gr at THW).
// ---------------------------------------------------------------------------
template<int S>
__global__ __launch_bounds__(256) void reduce_tanh_kernel(
    const float* __restrict__ pbuf,
    float* __restrict__ gbuf,
    const float* __restrict__ b_l,
    const float* __restrict__ b_r)
{
    const int i = blockIdx.x * 256 + threadIdx.x;
    const float4* p4 = (const float4*)pbuf;
    float4* g4 = (float4*)gbuf;

    float4 a = {0.f,0.f,0.f,0.f}, b = {0.f,0.f,0.f,0.f};
    #pragma unroll
    for (int g = 0; g < S; ++g) {
        float4 va = p4[(size_t)g       * PL4 + i];
        float4 vb = p4[(size_t)(S + g) * PL4 + i];
        a.x += va.x; a.y += va.y; a.z += va.z; a.w += va.w;
        b.x += vb.x; b.y += vb.y; b.z += vb.z; b.w += vb.w;
    }
    const float bl = b_l[0], br = b_r[0];
    float4 gl, gr;
    gl.x = tanhf(a.x + bl); gl.y = tanhf(a.y + bl);
    gl.z = tanhf(a.z + bl); gl.w = tanhf(a.w + bl);
    gr.x = tanhf(b.x + br); gr.y = tanhf(b.y + br);
    gr.z = tanhf(b.z + br); gr.w = tanhf(b.w + br);
    g4[i]       = gl;
    g4[PL4 + i] = gr;
}

// ---------------------------------------------------------------------------
// K3: combine (c < 128): thread owns (c,h,w4), iterates 16 t's carrying
// x/g in registers; NT stores (out never re-read); x reads cached (L3-warm).
// ---------------------------------------------------------------------------
__global__ __launch_bounds__(256) void combine_kernel(
    const float* __restrict__ x,
    const float* __restrict__ g,
    float* __restrict__ out)
{
    const int tid = blockIdx.x * 256 + threadIdx.x;   // c in [0,128)
    const int t0  = blockIdx.y * 16;
    const int c   = tid / HW4;
    const int gb  = tid - c * HW4;

    const float4* x4 = (const float4*)x;
    nt_float4*    on4 = (nt_float4*)out;
    const size_t  base = tid;

    if (c < 64) {
        const float4* gl4 = (const float4*)g;
        float4 xv = x4[(size_t)t0 * TS4 + base];
        float4 g0 = gl4[t0 * HW4 + gb];
        #pragma unroll 4
        for (int i = 0; i < 16; ++i) {
            const int t  = t0 + i;
            const int tp = (t + 1) & 63;
            float4 xn = x4[(size_t)tp * TS4 + base];
            float4 g1 = gl4[tp * HW4 + gb];
            nt_float4 r;
            r.x = xv.x - g0.x * xv.x + g1.x * xn.x;
            r.y = xv.y - g0.y * xv.y + g1.y * xn.y;
            r.z = xv.z - g0.z * xv.z + g1.z * xn.z;
            r.w = xv.w - g0.w * xv.w + g1.w * xn.w;
            __builtin_nontemporal_store(r, &on4[(size_t)t * TS4 + base]);
            xv = xn; g0 = g1;
        }
    } else {
        const float4* gr4 = (const float4*)(g + THW);
        const int tmi = (t0 + 63) & 63;
        float4 xm = x4[(size_t)tmi * TS4 + base];
        float4 gm = gr4[tmi * HW4 + gb];
        #pragma unroll 4
        for (int i = 0; i < 16; ++i) {
            const int t = t0 + i;
            float4 xv = x4[(size_t)t * TS4 + base];
            float4 g0 = gr4[t * HW4 + gb];
            nt_float4 r;
            r.x = xv.x - g0.x * xv.x + gm.x * xm.x;
            r.y = xv.y - g0.y * xv.y + gm.y * xm.y;
            r.z = xv.z - g0.z * xv.z + gm.z * xm.z;
            r.w = xv.w - g0.w * xv.w + gm.w * xm.w;
            __builtin_nontemporal_store(r, &on4[(size_t)t * TS4 + base]);
            xm = xv; gm = g0;
        }
    }
}

template<int S>
static void launch_all(const float* x, const float* w_l, const float* b_l,
                       const float* w_r, const float* b_r,
                       float* out, float* ws, hipStream_t stream)
{
    float* pbuf = ws;                          // 2*S partial planes
    float* gbuf = ws + (size_t)(2 * S) * THW;  // 2 gate planes

    const int ngate = 2 * S * 32;
    const int gate_copy = ngate * 4096;        // f4 covered by gate blocks
    const int rem = NCOPY4 - gate_copy;        // divides 4096 exactly for S=4/8/16
    const int ncopy = rem / 4096;

    gate_copy_kernel<S><<<ngate + ncopy, 256, 0, stream>>>(x, w_l, w_r, pbuf, out);
    reduce_tanh_kernel<S><<<PL4 / 256, 256, 0, stream>>>(pbuf, gbuf, b_l, b_r);
    combine_kernel<<<dim3(392, 4), 256, 0, stream>>>(x, gbuf, out);
}

extern "C" void kernel_launch(void* const* d_in, const int* in_sizes, int n_in,
                              void* d_out, int out_size, void* d_ws, size_t ws_size,
                              hipStream_t stream) {
    const float* x   = (const float*)d_in[0];
    const float* w_l = (const float*)d_in[1];
    const float* b_l = (const float*)d_in[2];
    const float* w_r = (const float*)d_in[3];
    const float* b_r = (const float*)d_in[4];
    float* out = (float*)d_out;
    float* ws  = (float*)d_ws;

    const size_t plane_bytes = (size_t)THW * 4;
    if (ws_size >= 34 * plane_bytes)
        launch_all<16>(x, w_l, b_l, w_r, b_r, out, ws, stream);
    else if (ws_size >= 18 * plane_bytes)
        launch_all<8>(x, w_l, b_l, w_r, b_r, out, ws, stream);
    else
        launch_all<4>(x, w_l, b_l, w_r, b_r, out, ws, stream);
}